// Round 3
// baseline (166.193 us; speedup 1.0000x reference)
//
#include <hip/hip_runtime.h>
#include <math.h>

// Problem constants (B=64, J=17, H=W=128)
#define BJ    1088          // B*J heatmaps per input tensor
#define HW    16384         // 128*128
#define NTH   256           // threads per block (4 waves) -> 8 blocks/CU
#define V4PT  (HW / 4 / NTH)   // 16 float4 per thread
#define NWAVE (NTH / 64)

// Monotonic unsigned key for float bits: orders like float compare.
__device__ __forceinline__ unsigned int ford(unsigned int u) {
    return (u & 0x80000000u) ? ~u : (u | 0x80000000u);
}
__device__ __forceinline__ unsigned int ford_inv(unsigned int o) {
    return (o & 0x80000000u) ? (o & 0x7fffffffu) : ~o;
}

// One 256-thread block per heatmap; 8 blocks/CU so load/compute phases of
// co-resident blocks interleave. Pass 1: stream map from HBM, block
// (max,first-argmax) via packed u64 key. Pass 2: re-read map (L1/L2-hot)
// and accumulate masked distance sum with 1-instr sqrt.
__global__ __launch_bounds__(NTH, 8) void hm_stats(const float* __restrict__ outp,
                                                   const float* __restrict__ tgtp,
                                                   float* __restrict__ d)
{
    __shared__ unsigned long long rkey[NWAVE];
    __shared__ float rs[NWAVE];
    __shared__ float rc[NWAVE];

    const int map = blockIdx.x;       // [0, 2*BJ): first BJ = output(pred), rest = target(gt)
    const int t   = threadIdx.x;
    const float* __restrict__ src = (map < BJ)
        ? (outp + (size_t)map * HW)
        : (tgtp + (size_t)(map - BJ) * HW);
    const float4* __restrict__ src4 = (const float4*)src;

    // ---- pass 1: stream + local (max, first-idx); idx grows per thread so '>' keeps first
    float lmax = -INFINITY;
    int   lidx = 0;
#pragma unroll
    for (int cI = 0; cI < V4PT / 4; ++cI) {         // 4 chunks of 4 float4 in flight
        float4 v[4];
#pragma unroll
        for (int j = 0; j < 4; ++j) v[j] = src4[t + (cI * 4 + j) * NTH];
#pragma unroll
        for (int j = 0; j < 4; ++j) {
            const int base = (t + (cI * 4 + j) * NTH) << 2;
            if (v[j].x > lmax) { lmax = v[j].x; lidx = base;     }
            if (v[j].y > lmax) { lmax = v[j].y; lidx = base + 1; }
            if (v[j].z > lmax) { lmax = v[j].z; lidx = base + 2; }
            if (v[j].w > lmax) { lmax = v[j].w; lidx = base + 3; }
        }
    }

    // pack (ord(value) << 32) | ~idx : u64 max == (max value, then min idx)
    unsigned long long key =
        ((unsigned long long)ford(__float_as_uint(lmax)) << 32) |
        (unsigned int)~lidx;

#pragma unroll
    for (int off = 32; off >= 1; off >>= 1) {
        unsigned long long ok = __shfl_down(key, off, 64);
        key = (ok > key) ? ok : key;
    }
    const int wave = t >> 6;
    const int lane = t & 63;
    if (lane == 0) rkey[wave] = key;
    __syncthreads();
    // every thread folds the 4 wave keys (LDS broadcast) — no second barrier
    unsigned long long bkey = rkey[0];
#pragma unroll
    for (int w = 1; w < NWAVE; ++w) bkey = (rkey[w] > bkey) ? rkey[w] : bkey;

    const float maxv = __uint_as_float(ford_inv((unsigned int)(bkey >> 32)));
    const int   midx = (int)~(unsigned int)(bkey & 0xffffffffu);
    // reference: ym = idx // H, xm = idx % H  (H==128 stride)
    const float ym  = (float)(midx >> 7);
    const float xm  = (float)(midx & 127);
    const float thv = maxv * 0.5f;

    // ---- pass 2: re-read (L1/L2-hot) + masked distance sum, predicated
    float s = 0.0f;
    float c = 0.0f;
#pragma unroll
    for (int cI = 0; cI < V4PT / 4; ++cI) {
        float4 v[4];
#pragma unroll
        for (int j = 0; j < 4; ++j) v[j] = src4[t + (cI * 4 + j) * NTH];
#pragma unroll
        for (int j = 0; j < 4; ++j) {
            const int v4i = t + (cI * 4 + j) * NTH;
            // all 4 elems share a row (row = v4i*4/128 = v4i>>5)
            const float dy  = (float)(v4i >> 5) - ym;
            const float dy2 = dy * dy;
            const float cx  = (float)((v4i << 2) & 127) - xm;
            {
                const float dx = cx;
                const float dist = __builtin_amdgcn_sqrtf(fmaf(dx, dx, dy2));
                const float m = (v[j].x > thv) ? 1.0f : 0.0f;
                s = fmaf(m, dist, s);  c += m;
            }
            {
                const float dx = cx + 1.0f;
                const float dist = __builtin_amdgcn_sqrtf(fmaf(dx, dx, dy2));
                const float m = (v[j].y > thv) ? 1.0f : 0.0f;
                s = fmaf(m, dist, s);  c += m;
            }
            {
                const float dx = cx + 2.0f;
                const float dist = __builtin_amdgcn_sqrtf(fmaf(dx, dx, dy2));
                const float m = (v[j].z > thv) ? 1.0f : 0.0f;
                s = fmaf(m, dist, s);  c += m;
            }
            {
                const float dx = cx + 3.0f;
                const float dist = __builtin_amdgcn_sqrtf(fmaf(dx, dx, dy2));
                const float m = (v[j].w > thv) ? 1.0f : 0.0f;
                s = fmaf(m, dist, s);  c += m;
            }
        }
    }

#pragma unroll
    for (int off = 32; off >= 1; off >>= 1) {
        s += __shfl_down(s, off, 64);
        c += __shfl_down(c, off, 64);
    }
    if (lane == 0) { rs[wave] = s; rc[wave] = c; }
    __syncthreads();
    if (t == 0) {
#pragma unroll
        for (int w = 1; w < NWAVE; ++w) { s += rs[w]; c += rc[w]; }
        const float mean = s / fmaxf(c, 1.0f);
        const float dd   = (c > 0.0f) ? (mean / 181.02f) : 1.0f;   // MAX_DIST
        d[map] = (maxv > 0.0f) ? dd : 0.0f;
    }
}

// Single-block final reduction: sum |gt - pred| / J / B
__global__ __launch_bounds__(256) void loss_reduce(const float* __restrict__ d,
                                                   float* __restrict__ out)
{
    __shared__ float rs[4];
    const int t = threadIdx.x;
    float s = 0.0f;
    for (int i = t; i < BJ; i += 256)
        s += fabsf(d[BJ + i] - d[i]);
#pragma unroll
    for (int off = 32; off >= 1; off >>= 1)
        s += __shfl_down(s, off, 64);
    const int wave = t >> 6;
    const int lane = t & 63;
    if (lane == 0) rs[wave] = s;
    __syncthreads();
    if (t == 0) {
        s = rs[0] + rs[1] + rs[2] + rs[3];
        out[0] = s / 17.0f / 64.0f;   // / J / B, matching reference order
    }
}

extern "C" void kernel_launch(void* const* d_in, const int* in_sizes, int n_in,
                              void* d_out, int out_size, void* d_ws, size_t ws_size,
                              hipStream_t stream) {
    const float* outp = (const float*)d_in[0];   // output heatmaps [64,17,128,128] f32
    const float* tgtp = (const float*)d_in[1];   // target heatmaps
    float* d = (float*)d_ws;                     // 2*BJ floats scratch

    hm_stats<<<dim3(2 * BJ), dim3(NTH), 0, stream>>>(outp, tgtp, d);
    loss_reduce<<<dim3(1), dim3(256), 0, stream>>>(d, (float*)d_out);
}

// Round 4
// 160.031 us; speedup vs baseline: 1.0385x; 1.0385x over previous
//
#include <hip/hip_runtime.h>
#include <math.h>

// Problem constants (B=64, J=17, H=W=128)
#define BJ    1088            // B*J heatmaps per tensor; one block per (pred,gt) pair
#define HW    16384           // 128*128
#define NTH   512             // threads per block (8 waves)
#define C4    (HW / 4 / NTH)  // 8 float4 per thread per map
#define NWAVE (NTH / 64)      // 8

// Monotonic unsigned key for float bits: orders like float compare.
__device__ __forceinline__ unsigned int ford(unsigned int u) {
    return (u & 0x80000000u) ? ~u : (u | 0x80000000u);
}
__device__ __forceinline__ unsigned int ford_inv(unsigned int o) {
    return (o & 0x80000000u) ? (o & 0x7fffffffu) : ~o;
}

__global__ void zero_out(float* __restrict__ out) { out[0] = 0.0f; }

// One block per (pred,gt) map pair. Both 64 KB maps are loaded in ONE
// 32-deep float4 burst into REGISTERS (asm-pinned so the compiler cannot
// rematerialize pass 2 as a global re-read — R2's VGPR=20 showed it does).
// Then: u64-key (max,first-argmax) for both maps (one barrier), masked
// distance sums from registers (v_sqrt), and a single scaled atomicAdd of
// |d_gt - d_pred| into the loss. One HBM pass total, no second kernel pass.
__global__ __launch_bounds__(NTH, 4) void pair_loss(const float* __restrict__ outp,
                                                    const float* __restrict__ tgtp,
                                                    float* __restrict__ loss)
{
    __shared__ unsigned long long rkA[NWAVE], rkB[NWAVE];
    __shared__ float rsA[NWAVE], rcA[NWAVE], rsB[NWAVE], rcB[NWAVE];

    const int m = blockIdx.x;     // [0, BJ)
    const int t = threadIdx.x;
    const float4* __restrict__ A4 = (const float4*)(outp + (size_t)m * HW);
    const float4* __restrict__ B4 = (const float4*)(tgtp + (size_t)m * HW);

    // ---- single load burst: 16 float4 per thread outstanding (128 KB/block)
    float4 ra[C4], rb[C4];
#pragma unroll
    for (int i = 0; i < C4; ++i) ra[i] = A4[t + i * NTH];
#pragma unroll
    for (int i = 0; i < C4; ++i) rb[i] = B4[t + i * NTH];
#pragma unroll
    for (int i = 0; i < C4; ++i) {
        asm volatile("" : "+v"(ra[i].x), "+v"(ra[i].y), "+v"(ra[i].z), "+v"(ra[i].w));
        asm volatile("" : "+v"(rb[i].x), "+v"(rb[i].y), "+v"(rb[i].z), "+v"(rb[i].w));
    }

    // ---- per-thread (max, first-idx) scans; idx grows per thread so '>' keeps first
    float lmaxA = -INFINITY, lmaxB = -INFINITY;
    int   lidxA = 0,         lidxB = 0;
#pragma unroll
    for (int i = 0; i < C4; ++i) {
        const int base = (t + i * NTH) << 2;
        if (ra[i].x > lmaxA) { lmaxA = ra[i].x; lidxA = base;     }
        if (ra[i].y > lmaxA) { lmaxA = ra[i].y; lidxA = base + 1; }
        if (ra[i].z > lmaxA) { lmaxA = ra[i].z; lidxA = base + 2; }
        if (ra[i].w > lmaxA) { lmaxA = ra[i].w; lidxA = base + 3; }
        if (rb[i].x > lmaxB) { lmaxB = rb[i].x; lidxB = base;     }
        if (rb[i].y > lmaxB) { lmaxB = rb[i].y; lidxB = base + 1; }
        if (rb[i].z > lmaxB) { lmaxB = rb[i].z; lidxB = base + 2; }
        if (rb[i].w > lmaxB) { lmaxB = rb[i].w; lidxB = base + 3; }
    }

    // pack (ord(value) << 32) | ~idx : u64 max == (max value, then min idx)
    unsigned long long keyA =
        ((unsigned long long)ford(__float_as_uint(lmaxA)) << 32) | (unsigned int)~lidxA;
    unsigned long long keyB =
        ((unsigned long long)ford(__float_as_uint(lmaxB)) << 32) | (unsigned int)~lidxB;

#pragma unroll
    for (int off = 32; off >= 1; off >>= 1) {
        unsigned long long oA = __shfl_down(keyA, off, 64);
        unsigned long long oB = __shfl_down(keyB, off, 64);
        keyA = (oA > keyA) ? oA : keyA;
        keyB = (oB > keyB) ? oB : keyB;
    }
    const int wave = t >> 6;
    const int lane = t & 63;
    if (lane == 0) { rkA[wave] = keyA; rkB[wave] = keyB; }
    __syncthreads();
    // every thread folds the wave keys (LDS broadcast reads)
    unsigned long long bkA = rkA[0], bkB = rkB[0];
#pragma unroll
    for (int w = 1; w < NWAVE; ++w) {
        bkA = (rkA[w] > bkA) ? rkA[w] : bkA;
        bkB = (rkB[w] > bkB) ? rkB[w] : bkB;
    }

    const float maxA = __uint_as_float(ford_inv((unsigned int)(bkA >> 32)));
    const float maxB = __uint_as_float(ford_inv((unsigned int)(bkB >> 32)));
    const int   miA  = (int)~(unsigned int)(bkA & 0xffffffffu);
    const int   miB  = (int)~(unsigned int)(bkB & 0xffffffffu);
    // reference: ym = idx // H, xm = idx % H  (H==128 stride)
    const float ymA = (float)(miA >> 7), xmA = (float)(miA & 127), thA = maxA * 0.5f;
    const float ymB = (float)(miB >> 7), xmB = (float)(miB & 127), thB = maxB * 0.5f;

    // ---- masked distance sums from registers (predicated, 1-instr sqrt)
    float sA = 0.0f, cA = 0.0f, sB = 0.0f, cB = 0.0f;
#pragma unroll
    for (int i = 0; i < C4; ++i) {
        const int v4i = t + i * NTH;
        const float row = (float)(v4i >> 5);           // all 4 elems share a row
        const float cb  = (float)((v4i << 2) & 127);
        const float dyA = row - ymA, dyA2 = dyA * dyA;
        const float dyB = row - ymB, dyB2 = dyB * dyB;
#pragma unroll
        for (int j = 0; j < 4; ++j) {
            const float va = (j == 0) ? ra[i].x : (j == 1) ? ra[i].y : (j == 2) ? ra[i].z : ra[i].w;
            const float vb = (j == 0) ? rb[i].x : (j == 1) ? rb[i].y : (j == 2) ? rb[i].z : rb[i].w;
            const float dxA = cb + (float)j - xmA;
            const float dxB = cb + (float)j - xmB;
            const float dA  = __builtin_amdgcn_sqrtf(fmaf(dxA, dxA, dyA2));
            const float dB  = __builtin_amdgcn_sqrtf(fmaf(dxB, dxB, dyB2));
            const float mA  = (va > thA) ? 1.0f : 0.0f;
            const float mB  = (vb > thB) ? 1.0f : 0.0f;
            sA = fmaf(mA, dA, sA);  cA += mA;
            sB = fmaf(mB, dB, sB);  cB += mB;
        }
    }

#pragma unroll
    for (int off = 32; off >= 1; off >>= 1) {
        sA += __shfl_down(sA, off, 64);
        cA += __shfl_down(cA, off, 64);
        sB += __shfl_down(sB, off, 64);
        cB += __shfl_down(cB, off, 64);
    }
    if (lane == 0) { rsA[wave] = sA; rcA[wave] = cA; rsB[wave] = sB; rcB[wave] = cB; }
    __syncthreads();
    if (t == 0) {
#pragma unroll
        for (int w = 1; w < NWAVE; ++w) {
            sA += rsA[w]; cA += rcA[w]; sB += rsB[w]; cB += rcB[w];
        }
        const float meanA = sA / fmaxf(cA, 1.0f);
        const float meanB = sB / fmaxf(cB, 1.0f);
        float dPred = (cA > 0.0f) ? (meanA / 181.02f) : 1.0f;   // MAX_DIST
        float dGt   = (cB > 0.0f) ? (meanB / 181.02f) : 1.0f;
        dPred = (maxA > 0.0f) ? dPred : 0.0f;
        dGt   = (maxB > 0.0f) ? dGt   : 0.0f;
        atomicAdd(loss, fabsf(dGt - dPred) * (1.0f / 17.0f / 64.0f));  // / J / B
    }
}

extern "C" void kernel_launch(void* const* d_in, const int* in_sizes, int n_in,
                              void* d_out, int out_size, void* d_ws, size_t ws_size,
                              hipStream_t stream) {
    const float* outp = (const float*)d_in[0];   // output heatmaps [64,17,128,128] f32
    const float* tgtp = (const float*)d_in[1];   // target heatmaps
    float* loss = (float*)d_out;

    zero_out<<<dim3(1), dim3(1), 0, stream>>>(loss);
    pair_loss<<<dim3(BJ), dim3(NTH), 0, stream>>>(outp, tgtp, loss);
}